// Round 6
// baseline (120.143 us; speedup 1.0000x reference)
//
#include <hip/hip_runtime.h>

#define HD 10
#define C2 20
#define PIX (192*192)
#define NB 8
#define NPIX (NB*PIX)
#define CHW (NB*HD*PIX)
#define EPSB 1e-5f
#define BPB (PIX/256)        // blocks per (batch,half) image = 144

__device__ __forceinline__ float sigm(float x) {
    return __builtin_amdgcn_rcpf(1.0f + __expf(-x));
}
__device__ __forceinline__ float tanh_fast(float x) {
    return 1.0f - 2.0f * __builtin_amdgcn_rcpf(1.0f + __expf(2.0f * x));
}

// Single fused kernel, 1 pixel/thread, halves interleaved on grid.x.
// Weight/BN reads are wave-uniform with compile-time offsets -> scalar loads.
// xp part-loads software-pipelined depth 2 (statically named bufs -> registers).
// launch_bounds(256,3): VGPR cap ~170 so the prefetch + BN consts stay live
// without spill (round-4 spill was at ~190 live floats; this peaks ~135).
__global__ __launch_bounds__(256, 3) void half_kernel(
    const float* __restrict__ xf, const float* __restrict__ xh, const float* __restrict__ xp,
    const float* __restrict__ h_att, const float* __restrict__ p_att,
    const float* __restrict__ dW1, const float* __restrict__ dbn1,
    const float* __restrict__ dW2, const float* __restrict__ dbn2,
    const float* __restrict__ uW1, const float* __restrict__ ubn1,
    const float* __restrict__ uW2, const float* __restrict__ ubn2,
    const float* __restrict__ lW1, const float* __restrict__ lbn1,
    const float* __restrict__ lW2, const float* __restrict__ lbn2,
    const float* __restrict__ guWg, const float* __restrict__ gubg,
    const float* __restrict__ guWc, const float* __restrict__ gubc,
    const float* __restrict__ glWg, const float* __restrict__ glbg,
    const float* __restrict__ glWc, const float* __restrict__ glbc,
    float* __restrict__ out)
{
    const int bid  = blockIdx.x;
    const int half = bid & 1;                    // interleaved for load balance
    const int bx   = bid >> 1;
    const int b    = bx / BPB;                   // uniform per block
    const int s    = (bx - b * BPB) * 256 + threadIdx.x;
    const int base  = b * (HD*PIX) + s;          // [B,HD,P] tensors: + c*PIX
    const int abase = b * PIX + s;               // [*,B,1,P] attention maps

    // wave-uniform weight/BN pointers (selected by uniform `half`)
    const float* Wc1  = half ? lW1  : uW1;
    const float* cbn1 = half ? lbn1 : ubn1;
    const float* Wc2  = half ? lW2  : uW2;
    const float* cbn2 = half ? lbn2 : ubn2;
    const float* Wg = half ? glWg : guWg;
    const float* bg = half ? glbg : gubg;
    const float* Wc = half ? glWc : guWc;
    const float* bc = half ? glbc : gubc;

    const float* xhh = xh + half * CHW;
    float* outh = out + half * CHW;

    const int pstart = half ? 4 : 0;
    const int nparts = half ? 2 : 4;

#define LOAD_XP(BUF, PI)                                        \
    do {                                                        \
        _Pragma("unroll")                                       \
        for (int c = 0; c < HD; ++c)                            \
            BUF[c] = xp[(PI) * CHW + base + c*PIX];             \
    } while (0)

    float vxh[HD];
    #pragma unroll
    for (int c = 0; c < HD; ++c) vxh[c] = xhh[base + c*PIX];

    const float ha = h_att[(1 + half) * NPIX + abase];
    float catt = 0.f;
    {
        const int mstart = half ? 5 : 1;
        const int natt   = half ? 2 : 4;
        #pragma unroll
        for (int j = 0; j < 4; ++j)
            if (j < natt) catt += p_att[(mstart + j) * NPIX + abase];
    }

    // prefetch part 0's xp raw (in flight across the whole decomp block)
    float xpA[HD], xpB[HD];
    LOAD_XP(xpA, pstart + 0);

    // ---- decomposition block -> message accumulator m (BN applied inline) ----
    float m[HD];
    {
        float in[C2];
        #pragma unroll
        for (int c = 0; c < HD; ++c) { in[c] = xf[base + c*PIX] * ha; in[HD + c] = vxh[c]; }
        float h[C2];
        #pragma unroll
        for (int o = 0; o < C2; ++o) {
            float a = 0.f;
            #pragma unroll
            for (int k = 0; k < C2; ++k) a = fmaf(dW1[o*C2 + k], in[k], a);
            float sc = dbn1[o] * rsqrtf(dbn1[3*C2 + o] + EPSB);
            float tr = dbn1[C2 + o] - sc * dbn1[2*C2 + o];
            h[o] = fmaxf(fmaf(a, sc, tr), 0.f);
        }
        #pragma unroll
        for (int o = 0; o < HD; ++o) {
            float a = 0.f;
            #pragma unroll
            for (int k = 0; k < C2; ++k) a = fmaf(dW2[o*C2 + k], h[k], a);
            float sc = dbn2[o] * rsqrtf(dbn2[3*HD + o] + EPSB);
            float tr = dbn2[HD + o] - sc * dbn2[2*HD + o];
            m[o] = fmaxf(fmaf(a, sc, tr), 0.f);
        }
    }

    // ---- composition blocks (depth-2 pipelined over parts) ----
    {
        float s1[C2], s2[HD], t2[HD];            // uniform BN constants (reused)
        #pragma unroll
        for (int o = 0; o < C2; ++o)
            s1[o] = cbn1[o] * rsqrtf(cbn1[3*C2 + o] + EPSB);
        #pragma unroll
        for (int o = 0; o < HD; ++o) {
            s2[o] = cbn2[o] * rsqrtf(cbn2[3*HD + o] + EPSB);
            t2[o] = cbn2[HD + o] - s2[o] * cbn2[2*HD + o];
        }
        // pre[] = BN-affine of the shared xh-half of conv1 (t1 folded in)
        float pre[C2];
        #pragma unroll
        for (int o = 0; o < C2; ++o) {
            float a = 0.f;
            #pragma unroll
            for (int k = 0; k < HD; ++k) a = fmaf(Wc1[o*C2 + k], vxh[k], a);
            float t1 = cbn1[C2 + o] - s1[o] * cbn1[2*C2 + o];
            pre[o] = fmaf(a, s1[o], t1);
        }

#define COMP_PART(BUF)                                                      \
    do {                                                                    \
        _Pragma("unroll")                                                   \
        for (int c = 0; c < HD; ++c) BUF[c] *= catt;                        \
        float hcb[C2];                                                      \
        _Pragma("unroll")                                                   \
        for (int o = 0; o < C2; ++o) {                                      \
            float a = 0.f;                                                  \
            _Pragma("unroll")                                               \
            for (int k = 0; k < HD; ++k)                                    \
                a = fmaf(Wc1[o*C2 + HD + k], BUF[k], a);                    \
            hcb[o] = fmaxf(fmaf(a, s1[o], pre[o]), 0.f);                    \
        }                                                                   \
        _Pragma("unroll")                                                   \
        for (int o = 0; o < HD; ++o) {                                      \
            float a = 0.f;                                                  \
            _Pragma("unroll")                                               \
            for (int k = 0; k < C2; ++k)                                    \
                a = fmaf(Wc2[o*C2 + k], hcb[k], a);                         \
            m[o] += fmaxf(fmaf(a, s2[o], t2[o]), 0.f);                      \
        }                                                                   \
    } while (0)

        LOAD_XP(xpB, pstart + 1);                // both halves have >= 2 parts
        COMP_PART(xpA);
        if (nparts > 2) {                        // upper half only (uniform)
            LOAD_XP(xpA, pstart + 2);
            COMP_PART(xpB);
            LOAD_XP(xpB, pstart + 3);
            COMP_PART(xpA);
            COMP_PART(xpB);
        } else {
            COMP_PART(xpB);
        }
#undef COMP_PART
    }

    // ---- GRU ----
    float g[C2];
    #pragma unroll
    for (int o = 0; o < C2; ++o) {
        float a = bg[o];
        #pragma unroll
        for (int k = 0; k < HD; ++k) a = fmaf(Wg[o*C2 + k], m[k], a);
        #pragma unroll
        for (int k = 0; k < HD; ++k) a = fmaf(Wg[o*C2 + HD + k], vxh[k], a);
        g[o] = sigm(a);
    }
    float rh[HD];
    #pragma unroll
    for (int k = 0; k < HD; ++k) rh[k] = g[k] * vxh[k];
    #pragma unroll
    for (int o = 0; o < HD; ++o) {
        float a = bc[o];
        #pragma unroll
        for (int k = 0; k < HD; ++k) a = fmaf(Wc[o*C2 + k], m[k], a);
        #pragma unroll
        for (int k = 0; k < HD; ++k) a = fmaf(Wc[o*C2 + HD + k], rh[k], a);
        float c = tanh_fast(a);
        float u = g[HD + o];
        outh[base + o*PIX] = fmaf(u, c - vxh[o], vxh[o]);   // (1-u)*h + u*c
    }
#undef LOAD_XP
}

extern "C" void kernel_launch(void* const* d_in, const int* in_sizes, int n_in,
                              void* d_out, int out_size, void* d_ws, size_t ws_size,
                              hipStream_t stream) {
    const float* xf    = (const float*)d_in[0];
    const float* xh    = (const float*)d_in[1];
    const float* xp    = (const float*)d_in[2];
    const float* h_att = (const float*)d_in[3];
    const float* p_att = (const float*)d_in[4];
    const float* dW1   = (const float*)d_in[5];
    const float* dbn1  = (const float*)d_in[6];
    const float* dW2   = (const float*)d_in[7];
    const float* dbn2  = (const float*)d_in[8];
    const float* uW1   = (const float*)d_in[9];
    const float* ubn1  = (const float*)d_in[10];
    const float* uW2   = (const float*)d_in[11];
    const float* ubn2  = (const float*)d_in[12];
    const float* lW1   = (const float*)d_in[13];
    const float* lbn1  = (const float*)d_in[14];
    const float* lW2   = (const float*)d_in[15];
    const float* lbn2  = (const float*)d_in[16];
    const float* guWg  = (const float*)d_in[17];
    const float* gubg  = (const float*)d_in[18];
    const float* guWc  = (const float*)d_in[19];
    const float* gubc  = (const float*)d_in[20];
    const float* glWg  = (const float*)d_in[21];
    const float* glbg  = (const float*)d_in[22];
    const float* glWc  = (const float*)d_in[23];
    const float* glbc  = (const float*)d_in[24];

    dim3 grid((NPIX / 256) * 2), block(256);
    half_kernel<<<grid, block, 0, stream>>>(
        xf, xh, xp, h_att, p_att,
        dW1, dbn1, dW2, dbn2,
        uW1, ubn1, uW2, ubn2,
        lW1, lbn1, lW2, lbn2,
        guWg, gubg, guWc, gubc,
        glWg, glbg, glWc, glbc,
        (float*)d_out);
}

// Round 7
// 107.709 us; speedup vs baseline: 1.1154x; 1.1154x over previous
//
#include <hip/hip_runtime.h>

#define HD 10
#define C2 20
#define PIX (192*192)
#define NB 8
#define NPIX (NB*PIX)
#define CHW (NB*HD*PIX)
#define EPSB 1e-5f
#define BPB (PIX/256)        // blocks per (batch,half) image = 144

__device__ __forceinline__ float rsq_fast(float x) {
    return __builtin_amdgcn_rsqf(x);        // single v_rsq_f32 (BN vars in [0.5,1.5])
}
__device__ __forceinline__ float sigm(float x) {
    return __builtin_amdgcn_rcpf(1.0f + __expf(-x));
}
__device__ __forceinline__ float tanh_fast(float x) {
    return 1.0f - 2.0f * __builtin_amdgcn_rcpf(1.0f + __expf(2.0f * x));
}

// Single fused kernel, 1 pixel/thread, halves interleaved on grid.x (r5 structure).
// Weight/BN reads are wave-uniform with compile-time offsets -> scalar loads.
// This round: instruction-count trims only (fast rsq, catt folded into BN scale,
// no in[] copy). No manual pipelining, no launch_bounds cap (r6 lesson).
__global__ __launch_bounds__(256) void half_kernel(
    const float* __restrict__ xf, const float* __restrict__ xh, const float* __restrict__ xp,
    const float* __restrict__ h_att, const float* __restrict__ p_att,
    const float* __restrict__ dW1, const float* __restrict__ dbn1,
    const float* __restrict__ dW2, const float* __restrict__ dbn2,
    const float* __restrict__ uW1, const float* __restrict__ ubn1,
    const float* __restrict__ uW2, const float* __restrict__ ubn2,
    const float* __restrict__ lW1, const float* __restrict__ lbn1,
    const float* __restrict__ lW2, const float* __restrict__ lbn2,
    const float* __restrict__ guWg, const float* __restrict__ gubg,
    const float* __restrict__ guWc, const float* __restrict__ gubc,
    const float* __restrict__ glWg, const float* __restrict__ glbg,
    const float* __restrict__ glWc, const float* __restrict__ glbc,
    float* __restrict__ out)
{
    const int bid  = blockIdx.x;
    const int half = bid & 1;                    // interleaved for load balance
    const int bx   = bid >> 1;
    const int b    = bx / BPB;                   // uniform per block
    const int s    = (bx - b * BPB) * 256 + threadIdx.x;
    const int base  = b * (HD*PIX) + s;          // [B,HD,P] tensors: + c*PIX
    const int abase = b * PIX + s;               // [*,B,1,P] attention maps

    // wave-uniform weight/BN pointers (selected by uniform `half`)
    const float* Wc1  = half ? lW1  : uW1;
    const float* cbn1 = half ? lbn1 : ubn1;
    const float* Wc2  = half ? lW2  : uW2;
    const float* cbn2 = half ? lbn2 : ubn2;
    const float* Wg = half ? glWg : guWg;
    const float* bg = half ? glbg : gubg;
    const float* Wc = half ? glWc : guWc;
    const float* bc = half ? glbc : gubc;

    const float* xhh = xh + half * CHW;
    float* outh = out + half * CHW;

    float vxh[HD];
    #pragma unroll
    for (int c = 0; c < HD; ++c) vxh[c] = xhh[base + c*PIX];

    const float ha = h_att[(1 + half) * NPIX + abase];
    float catt = 0.f;
    {
        const int mstart = half ? 5 : 1;
        const int natt   = half ? 2 : 4;
        #pragma unroll
        for (int j = 0; j < 4; ++j)
            if (j < natt) catt += p_att[(mstart + j) * NPIX + abase];
    }

    // ---- decomposition block -> message accumulator m (BN applied inline) ----
    float m[HD];
    {
        float xfha[HD];
        #pragma unroll
        for (int c = 0; c < HD; ++c) xfha[c] = xf[base + c*PIX] * ha;
        float h[C2];
        #pragma unroll
        for (int o = 0; o < C2; ++o) {
            float a = 0.f;
            #pragma unroll
            for (int k = 0; k < HD; ++k) a = fmaf(dW1[o*C2 + k], xfha[k], a);
            #pragma unroll
            for (int k = 0; k < HD; ++k) a = fmaf(dW1[o*C2 + HD + k], vxh[k], a);
            float sc = dbn1[o] * rsq_fast(dbn1[3*C2 + o] + EPSB);
            float tr = dbn1[C2 + o] - sc * dbn1[2*C2 + o];
            h[o] = fmaxf(fmaf(a, sc, tr), 0.f);
        }
        #pragma unroll
        for (int o = 0; o < HD; ++o) {
            float a = 0.f;
            #pragma unroll
            for (int k = 0; k < C2; ++k) a = fmaf(dW2[o*C2 + k], h[k], a);
            float sc = dbn2[o] * rsq_fast(dbn2[3*HD + o] + EPSB);
            float tr = dbn2[HD + o] - sc * dbn2[2*HD + o];
            m[o] = fmaxf(fmaf(a, sc, tr), 0.f);
        }
    }

    // ---- composition blocks (part loop statically unrolled, uniform guards) ----
    {
        float s1[C2], s1c[C2], s2[HD], t2[HD];   // BN constants (reused across parts)
        #pragma unroll
        for (int o = 0; o < C2; ++o) {
            s1[o]  = cbn1[o] * rsq_fast(cbn1[3*C2 + o] + EPSB);
            s1c[o] = s1[o] * catt;               // catt folded into part-conv scale
        }
        #pragma unroll
        for (int o = 0; o < HD; ++o) {
            s2[o] = cbn2[o] * rsq_fast(cbn2[3*HD + o] + EPSB);
            t2[o] = cbn2[HD + o] - s2[o] * cbn2[2*HD + o];
        }
        // pre[] = BN-affine of the shared xh-half of conv1 (t1 folded in)
        float pre[C2];
        #pragma unroll
        for (int o = 0; o < C2; ++o) {
            float a = 0.f;
            #pragma unroll
            for (int k = 0; k < HD; ++k) a = fmaf(Wc1[o*C2 + k], vxh[k], a);
            float t1 = cbn1[C2 + o] - s1[o] * cbn1[2*C2 + o];
            pre[o] = fmaf(a, s1[o], t1);
        }
        const int pstart = half ? 4 : 0;
        const int nparts = half ? 2 : 4;
        #pragma unroll
        for (int i = 0; i < 4; ++i) {
            if (i < nparts) {                    // wave-uniform guard
                float xpi[HD];                   // raw loads; catt is in s1c
                #pragma unroll
                for (int c = 0; c < HD; ++c)
                    xpi[c] = xp[(pstart + i) * CHW + base + c*PIX];
                float h[C2];
                #pragma unroll
                for (int o = 0; o < C2; ++o) {
                    float a = 0.f;
                    #pragma unroll
                    for (int k = 0; k < HD; ++k) a = fmaf(Wc1[o*C2 + HD + k], xpi[k], a);
                    h[o] = fmaxf(fmaf(a, s1c[o], pre[o]), 0.f);
                }
                #pragma unroll
                for (int o = 0; o < HD; ++o) {
                    float a = 0.f;
                    #pragma unroll
                    for (int k = 0; k < C2; ++k) a = fmaf(Wc2[o*C2 + k], h[k], a);
                    m[o] += fmaxf(fmaf(a, s2[o], t2[o]), 0.f);
                }
            }
        }
    }

    // ---- GRU ----
    float g[C2];
    #pragma unroll
    for (int o = 0; o < C2; ++o) {
        float a = bg[o];
        #pragma unroll
        for (int k = 0; k < HD; ++k) a = fmaf(Wg[o*C2 + k], m[k], a);
        #pragma unroll
        for (int k = 0; k < HD; ++k) a = fmaf(Wg[o*C2 + HD + k], vxh[k], a);
        g[o] = sigm(a);
    }
    float rh[HD];
    #pragma unroll
    for (int k = 0; k < HD; ++k) rh[k] = g[k] * vxh[k];
    #pragma unroll
    for (int o = 0; o < HD; ++o) {
        float a = bc[o];
        #pragma unroll
        for (int k = 0; k < HD; ++k) a = fmaf(Wc[o*C2 + k], m[k], a);
        #pragma unroll
        for (int k = 0; k < HD; ++k) a = fmaf(Wc[o*C2 + HD + k], rh[k], a);
        float c = tanh_fast(a);
        float u = g[HD + o];
        outh[base + o*PIX] = fmaf(u, c - vxh[o], vxh[o]);   // (1-u)*h + u*c
    }
}

extern "C" void kernel_launch(void* const* d_in, const int* in_sizes, int n_in,
                              void* d_out, int out_size, void* d_ws, size_t ws_size,
                              hipStream_t stream) {
    const float* xf    = (const float*)d_in[0];
    const float* xh    = (const float*)d_in[1];
    const float* xp    = (const float*)d_in[2];
    const float* h_att = (const float*)d_in[3];
    const float* p_att = (const float*)d_in[4];
    const float* dW1   = (const float*)d_in[5];
    const float* dbn1  = (const float*)d_in[6];
    const float* dW2   = (const float*)d_in[7];
    const float* dbn2  = (const float*)d_in[8];
    const float* uW1   = (const float*)d_in[9];
    const float* ubn1  = (const float*)d_in[10];
    const float* uW2   = (const float*)d_in[11];
    const float* ubn2  = (const float*)d_in[12];
    const float* lW1   = (const float*)d_in[13];
    const float* lbn1  = (const float*)d_in[14];
    const float* lW2   = (const float*)d_in[15];
    const float* lbn2  = (const float*)d_in[16];
    const float* guWg  = (const float*)d_in[17];
    const float* gubg  = (const float*)d_in[18];
    const float* guWc  = (const float*)d_in[19];
    const float* gubc  = (const float*)d_in[20];
    const float* glWg  = (const float*)d_in[21];
    const float* glbg  = (const float*)d_in[22];
    const float* glWc  = (const float*)d_in[23];
    const float* glbc  = (const float*)d_in[24];

    dim3 grid((NPIX / 256) * 2), block(256);
    half_kernel<<<grid, block, 0, stream>>>(
        xf, xh, xp, h_att, p_att,
        dW1, dbn1, dW2, dbn2,
        uW1, ubn1, uW2, ubn2,
        lW1, lbn1, lW2, lbn2,
        guWg, gubg, guWc, gubc,
        glWg, glbg, glWc, glbc,
        (float*)d_out);
}